// Round 4
// baseline (1081.501 us; speedup 1.0000x reference)
//
#include <hip/hip_runtime.h>

// AggregateSet fused kernel, MI355X (gfx950).
// Shapes: B=1024, M_ELEM=128, D_IN=64, D_HID=256, H=8, D_K=D_V=64.
// R3: 512-thread blocks, ONE HEAD PER WAVE (8 waves). Weights partitioned by
// head (768KB/block L2 traffic, not 3MB as R2). Softmax wave-local -> a
// single __syncthreads() in the whole kernel. activ in shared LDS (64KB,
// XOR-swizzled, conflict-free ds_read_b128). Weights pre-packed in exact
// MFMA fragment order -> every B-frag load is a wave-contiguous 1KB stream.
// VGPR budget: aq[8]+ak[8]+pl[32] ~= 120, launch_bounds(512,4) caps at 128
// -> 16 waves/CU. K-permutation identical for A and B frags (cancels).

typedef __attribute__((ext_vector_type(8))) short bf16x8;
typedef __attribute__((ext_vector_type(4))) float f32x4;

#define XROW 8320
#define MASK_OFF 8192

static __device__ __forceinline__ short f2bf(float f) {
  union { float f; unsigned u; } v; v.f = f;
  unsigned r = v.u + 0x7FFFu + ((v.u >> 16) & 1u);  // RNE
  return (short)(r >> 16);
}
static __device__ __forceinline__ f32x4 splat4(float v) {
  f32x4 r = {v, v, v, v};
  return r;
}

// ---------------------------------------------------------------------------
// Weight prep: fp32 row-major W[k][n] -> bf16 in FRAGMENT ORDER.
// Wsub (K=64,N=256):  idx = t*1024 + ks1*512 + lg*128 + l15*8 + j
//                     n = 16t+l15, k = 32ks1+8lg+j         (16384 shorts)
// Wq/Wk/Wv (K=256,N=512): idx = t*4096 + ks*512 + lg*128 + l15*8 + j
//                     n = 16t+l15, k = 32ks+8lg+j          (131072 each)
// Layout: wt = [wsub | wq | wk | wv], 409600 shorts = 800KB in d_ws.
__global__ __launch_bounds__(256) void prep_weights(
    const float* __restrict__ Ws, const float* __restrict__ Wq,
    const float* __restrict__ Wk, const float* __restrict__ Wv,
    short* __restrict__ wt)
{
  int tid = blockIdx.x * 256 + threadIdx.x;   // grid is exactly 1600*256
  if (tid < 16384) {
    int t = tid >> 10, ks = (tid >> 9) & 1, lg = (tid >> 7) & 3;
    int l15 = (tid >> 3) & 15, j = tid & 7;
    int n = 16 * t + l15, k = 32 * ks + 8 * lg + j;
    wt[tid] = f2bf(Ws[k * 256 + n]);
  } else {
    int idx = tid - 16384;
    int m = idx >> 17;            // 0:q 1:k 2:v
    int i = idx & 131071;
    int t = i >> 12, ks = (i >> 9) & 7, lg = (i >> 7) & 3;
    int l15 = (i >> 3) & 15, j = i & 7;
    int n = 16 * t + l15, k = 32 * ks + 8 * lg + j;
    const float* W = (m == 0) ? Wq : (m == 1) ? Wk : Wv;
    wt[tid] = f2bf(W[k * 512 + n]);
  }
}

// A-frag (16x32) from swizzled shared activ: elem (e,k) at
// activ[e*256 + ((k>>3 ^ (e&15))<<3 | (k&7))]; frag k = 32ks+8lg+j.
static __device__ __forceinline__ bf16x8 ld_a(const short* activ,
                                              int e, int ks, int lg) {
  return *(const bf16x8*)(activ + e * 256 + ((((4 * ks + lg) ^ (e & 15))) << 3));
}

__global__ __launch_bounds__(512, 4) void fused_kernel(
    const float* __restrict__ x,
    const float* __restrict__ bsub, const float* __restrict__ bq,
    const float* __restrict__ bk,   const float* __restrict__ bv,
    const short* __restrict__ wt,   float* __restrict__ out)
{
  __shared__ short activ[128 * 256];   // 64KB, XOR-swizzled
  __shared__ float smask[128];

  const int b   = blockIdx.x;
  const int tid = threadIdx.x;
  const int w   = tid >> 6;       // wave 0..7  == head
  const int l   = tid & 63;
  const int l15 = l & 15;
  const int lg  = l >> 4;

  const float* xb  = x + (size_t)b * XROW;
  const short* wts = wt;
  const short* wtq = wt + 16384;
  const short* wtk = wtq + 131072;
  const short* wtv = wtk + 131072;

  if (tid < 128) smask[tid] = xb[MASK_OFF + tid];

  // ---------------- GEMM1: activ = xe @ Wsub + bsub ----------------------
  // wave w owns rows 16w..16w+15 (one m-tile).
  {
    bf16x8 a1[2];
    #pragma unroll
    for (int ks1 = 0; ks1 < 2; ++ks1) {
      int e = 16 * w + l15;
      const float* p = xb + e * 64 + 32 * ks1 + 8 * lg;
      float4 f0 = *(const float4*)p;
      float4 f1 = *(const float4*)(p + 4);
      bf16x8 t;
      t[0] = f2bf(f0.x); t[1] = f2bf(f0.y); t[2] = f2bf(f0.z); t[3] = f2bf(f0.w);
      t[4] = f2bf(f1.x); t[5] = f2bf(f1.y); t[6] = f2bf(f1.z); t[7] = f2bf(f1.w);
      a1[ks1] = t;
    }
    #pragma unroll 1
    for (int t = 0; t < 16; ++t) {
      f32x4 acc = splat4(bsub[16 * t + l15]);
      #pragma unroll
      for (int ks1 = 0; ks1 < 2; ++ks1) {
        bf16x8 bfw = *(const bf16x8*)(wts + t * 1024 + ks1 * 512 + lg * 128 + l15 * 8);
        acc = __builtin_amdgcn_mfma_f32_16x16x32_bf16(a1[ks1], bfw, acc, 0, 0, 0);
      }
      #pragma unroll
      for (int r = 0; r < 4; ++r) {
        int e   = 16 * w + 4 * lg + r;
        int col = 16 * t + l15;
        activ[e * 256 + ((((col >> 3) ^ (e & 15)) << 3) | (col & 7))] = f2bf(acc[r]);
      }
    }
  }
  __syncthreads();   // the only barrier

  // elem_frac (exact: mask is 0/1) — wave 0 lanes
  if (tid < 64) {
    float s = smask[tid] + smask[tid + 64];
    #pragma unroll
    for (int off = 32; off > 0; off >>= 1) s += __shfl_xor(s, off);
    if (tid == 0) out[b * 513 + 512] = s * (1.f / 128.f);
  }

  const int h = w;

  // ---------------- qk: scores for all 128 rows, this wave's head --------
  float pl[32];   // rows e = 16mt + 4lg + r, i = mt*4+r (d-partials on l15)
  #pragma unroll
  for (int i = 0; i < 32; ++i) pl[i] = 0.f;

  #pragma unroll 1
  for (int nt = 0; nt < 4; ++nt) {
    int n = h * 64 + 16 * nt + l15;
    int tq = 4 * h + nt;
    const short* baq = wtq + tq * 4096 + lg * 128 + l15 * 8;
    const short* bak = wtk + tq * 4096 + lg * 128 + l15 * 8;
    f32x4 aq[8], ak[8];
    float biq = bq[n], bik = bk[n];
    #pragma unroll
    for (int mt = 0; mt < 8; ++mt) { aq[mt] = splat4(biq); ak[mt] = splat4(bik); }
    #pragma unroll
    for (int ks = 0; ks < 8; ++ks) {
      bf16x8 bqf = *(const bf16x8*)(baq + ks * 512);
      bf16x8 bkf = *(const bf16x8*)(bak + ks * 512);
      #pragma unroll
      for (int mt = 0; mt < 8; ++mt) {
        bf16x8 af = ld_a(activ, 16 * mt + l15, ks, lg);
        aq[mt] = __builtin_amdgcn_mfma_f32_16x16x32_bf16(af, bqf, aq[mt], 0, 0, 0);
        ak[mt] = __builtin_amdgcn_mfma_f32_16x16x32_bf16(af, bkf, ak[mt], 0, 0, 0);
      }
    }
    #pragma unroll
    for (int mt = 0; mt < 8; ++mt)
      #pragma unroll
      for (int r = 0; r < 4; ++r)
        pl[mt * 4 + r] += aq[mt][r] * ak[mt][r];
  }
  // reduce d-partials over 16 lanes; scale 1/sqrt(64)
  #pragma unroll
  for (int i = 0; i < 32; ++i) {
    float s = pl[i];
    s += __shfl_xor(s, 1);
    s += __shfl_xor(s, 2);
    s += __shfl_xor(s, 4);
    s += __shfl_xor(s, 8);
    pl[i] = s * 0.125f;
  }

  // ---------------- masked softmax, fully wave-local ----------------------
  unsigned mm = 0;   // mask bits for this lane's 32 rows
  #pragma unroll
  for (int mt = 0; mt < 8; ++mt)
    #pragma unroll
    for (int r = 0; r < 4; ++r)
      if (smask[16 * mt + 4 * lg + r] > 0.f) mm |= (1u << (mt * 4 + r));

  float zmax = 0.f;  // relu floor
  #pragma unroll
  for (int i = 0; i < 32; ++i)
    zmax = fmaxf(zmax, ((mm >> i) & 1) ? pl[i] : 0.f);
  zmax = fmaxf(zmax, __shfl_xor(zmax, 16));
  zmax = fmaxf(zmax, __shfl_xor(zmax, 32));

  float esum = 0.f;
  #pragma unroll
  for (int i = 0; i < 32; ++i) {
    float ev = ((mm >> i) & 1) ? __expf(pl[i] - zmax) : 0.f;
    pl[i] = ev;
    esum += ev;
  }
  esum += __shfl_xor(esum, 16);
  esum += __shfl_xor(esum, 32);
  float inv = 1.f / (esum + 1.f);
  #pragma unroll
  for (int i = 0; i < 32; ++i) pl[i] *= inv;

  // ---------------- v: project + attn-weighted pool, direct out -----------
  #pragma unroll 1
  for (int nt = 0; nt < 4; ++nt) {
    int n = h * 64 + 16 * nt + l15;
    int tv = 4 * h + nt;
    const short* bav = wtv + tv * 4096 + lg * 128 + l15 * 8;
    f32x4 av[8];
    float biv = bv[n];
    #pragma unroll
    for (int mt = 0; mt < 8; ++mt) av[mt] = splat4(biv);
    #pragma unroll
    for (int ks = 0; ks < 8; ++ks) {
      bf16x8 bvf = *(const bf16x8*)(bav + ks * 512);
      #pragma unroll
      for (int mt = 0; mt < 8; ++mt) {
        bf16x8 af = ld_a(activ, 16 * mt + l15, ks, lg);
        av[mt] = __builtin_amdgcn_mfma_f32_16x16x32_bf16(af, bvf, av[mt], 0, 0, 0);
      }
    }
    float t = 0.f;
    #pragma unroll
    for (int mt = 0; mt < 8; ++mt)
      #pragma unroll
      for (int r = 0; r < 4; ++r)
        t += pl[mt * 4 + r] * av[mt][r];
    t += __shfl_xor(t, 16);
    t += __shfl_xor(t, 32);
    if (lg == 0) out[b * 513 + h * 64 + 16 * nt + l15] = t;
  }
}

extern "C" void kernel_launch(void* const* d_in, const int* in_sizes, int n_in,
                              void* d_out, int out_size, void* d_ws, size_t ws_size,
                              hipStream_t stream) {
  (void)in_sizes; (void)n_in; (void)out_size; (void)ws_size;
  const float* x    = (const float*)d_in[0];
  const float* Wsub = (const float*)d_in[1];
  const float* bsub = (const float*)d_in[2];
  const float* Wq   = (const float*)d_in[3];
  const float* bq   = (const float*)d_in[4];
  const float* Wk   = (const float*)d_in[5];
  const float* bk   = (const float*)d_in[6];
  const float* Wv   = (const float*)d_in[7];
  const float* bv   = (const float*)d_in[8];
  float* out = (float*)d_out;
  short* wt  = (short*)d_ws;   // 800 KB used

  prep_weights<<<1600, 256, 0, stream>>>(Wsub, Wq, Wk, Wv, wt);
  fused_kernel<<<1024, 512, 0, stream>>>(x, bsub, bq, bk, bv, wt, out);
}

// Round 5
// 190.196 us; speedup vs baseline: 5.6862x; 5.6862x over previous
//
#include <hip/hip_runtime.h>

// AggregateSet fused kernel, MI355X (gfx950).
// Shapes: B=1024, M_ELEM=128, D_IN=64, D_HID=256, H=8, D_K=D_V=64.
// R4 = R3 structure (512 thr, one head per wave, single barrier, weights
// pre-packed in MFMA fragment order) with the register strangulation fixed:
// __launch_bounds__ 2nd arg is MIN BLOCKS/CU (standard CUDA semantics —
// R3's (512,4) forced a 64-VGPR cap and 1.3GB of spills). (512,2) -> 128
// cap. GEMM2 restructured so peak live ~90 VGPRs: qk processes m-tiles in
// halves (aq[4]+ak[4]), v processes nt-PAIRS with m-halves (av[2][4]).
// K-permutation identical for A and B frags (cancels inside MFMA).

typedef __attribute__((ext_vector_type(8))) short bf16x8;
typedef __attribute__((ext_vector_type(4))) float f32x4;

#define XROW 8320
#define MASK_OFF 8192

static __device__ __forceinline__ short f2bf(float f) {
  union { float f; unsigned u; } v; v.f = f;
  unsigned r = v.u + 0x7FFFu + ((v.u >> 16) & 1u);  // RNE
  return (short)(r >> 16);
}
static __device__ __forceinline__ f32x4 splat4(float v) {
  f32x4 r = {v, v, v, v};
  return r;
}

// ---------------------------------------------------------------------------
// Weight prep: fp32 row-major W[k][n] -> bf16 in FRAGMENT ORDER.
// Wsub (K=64,N=256):  idx = t*1024 + ks1*512 + lg*128 + l15*8 + j
//                     n = 16t+l15, k = 32ks1+8lg+j         (16384 shorts)
// Wq/Wk/Wv (K=256,N=512): idx = t*4096 + ks*512 + lg*128 + l15*8 + j
//                     n = 16t+l15, k = 32ks+8lg+j          (131072 each)
__global__ __launch_bounds__(256) void prep_weights(
    const float* __restrict__ Ws, const float* __restrict__ Wq,
    const float* __restrict__ Wk, const float* __restrict__ Wv,
    short* __restrict__ wt)
{
  int tid = blockIdx.x * 256 + threadIdx.x;   // grid is exactly 1600*256
  if (tid < 16384) {
    int t = tid >> 10, ks = (tid >> 9) & 1, lg = (tid >> 7) & 3;
    int l15 = (tid >> 3) & 15, j = tid & 7;
    int n = 16 * t + l15, k = 32 * ks + 8 * lg + j;
    wt[tid] = f2bf(Ws[k * 256 + n]);
  } else {
    int idx = tid - 16384;
    int m = idx >> 17;            // 0:q 1:k 2:v
    int i = idx & 131071;
    int t = i >> 12, ks = (i >> 9) & 7, lg = (i >> 7) & 3;
    int l15 = (i >> 3) & 15, j = i & 7;
    int n = 16 * t + l15, k = 32 * ks + 8 * lg + j;
    const float* W = (m == 0) ? Wq : (m == 1) ? Wk : Wv;
    wt[tid] = f2bf(W[k * 512 + n]);
  }
}

// A-frag (16x32) from swizzled shared activ: elem (e,k) at
// activ[e*256 + ((k>>3 ^ (e&15))<<3 | (k&7))]; frag k = 32ks+8lg+j.
static __device__ __forceinline__ bf16x8 ld_a(const short* activ,
                                              int e, int ks, int lg) {
  return *(const bf16x8*)(activ + e * 256 + ((((4 * ks + lg) ^ (e & 15))) << 3));
}

__global__ __launch_bounds__(512, 2) void fused_kernel(
    const float* __restrict__ x,
    const float* __restrict__ bsub, const float* __restrict__ bq,
    const float* __restrict__ bk,   const float* __restrict__ bv,
    const short* __restrict__ wt,   float* __restrict__ out)
{
  __shared__ short activ[128 * 256];   // 64KB, XOR-swizzled (16B granule)
  __shared__ float smask[128];

  const int b   = blockIdx.x;
  const int tid = threadIdx.x;
  const int w   = tid >> 6;       // wave 0..7  == head
  const int l   = tid & 63;
  const int l15 = l & 15;
  const int lg  = l >> 4;

  const float* xb  = x + (size_t)b * XROW;
  const short* wts = wt;
  const short* wtq = wt + 16384;
  const short* wtk = wtq + 131072;
  const short* wtv = wtk + 131072;

  if (tid < 128) smask[tid] = xb[MASK_OFF + tid];

  // ---------------- GEMM1: activ = xe @ Wsub + bsub ----------------------
  // wave w owns rows 16w..16w+15 (one m-tile).
  {
    bf16x8 a1[2];
    #pragma unroll
    for (int ks1 = 0; ks1 < 2; ++ks1) {
      int e = 16 * w + l15;
      const float* p = xb + e * 64 + 32 * ks1 + 8 * lg;
      float4 f0 = *(const float4*)p;
      float4 f1 = *(const float4*)(p + 4);
      bf16x8 t;
      t[0] = f2bf(f0.x); t[1] = f2bf(f0.y); t[2] = f2bf(f0.z); t[3] = f2bf(f0.w);
      t[4] = f2bf(f1.x); t[5] = f2bf(f1.y); t[6] = f2bf(f1.z); t[7] = f2bf(f1.w);
      a1[ks1] = t;
    }
    #pragma unroll 1
    for (int t = 0; t < 16; ++t) {
      f32x4 acc = splat4(bsub[16 * t + l15]);
      #pragma unroll
      for (int ks1 = 0; ks1 < 2; ++ks1) {
        bf16x8 bfw = *(const bf16x8*)(wts + t * 1024 + ks1 * 512 + lg * 128 + l15 * 8);
        acc = __builtin_amdgcn_mfma_f32_16x16x32_bf16(a1[ks1], bfw, acc, 0, 0, 0);
      }
      #pragma unroll
      for (int r = 0; r < 4; ++r) {
        int e   = 16 * w + 4 * lg + r;
        int col = 16 * t + l15;
        activ[e * 256 + ((((col >> 3) ^ (e & 15)) << 3) | (col & 7))] = f2bf(acc[r]);
      }
    }
  }
  __syncthreads();   // the only barrier

  // elem_frac (exact: mask is 0/1) — wave 0 lanes
  if (tid < 64) {
    float s = smask[tid] + smask[tid + 64];
    #pragma unroll
    for (int off = 32; off > 0; off >>= 1) s += __shfl_xor(s, off);
    if (tid == 0) out[b * 513 + 512] = s * (1.f / 128.f);
  }

  const int h = w;

  // lane's mask bits for its 32 rows e = 16mt + 4lg + r  (i = mt*4+r)
  unsigned mm = 0;
  #pragma unroll
  for (int mt = 0; mt < 8; ++mt)
    #pragma unroll
    for (int r = 0; r < 4; ++r)
      if (smask[16 * mt + 4 * lg + r] > 0.f) mm |= (1u << (mt * 4 + r));

  // ---------------- qk: scores for all 128 rows, this wave's head --------
  float pl[32];
  #pragma unroll
  for (int i = 0; i < 32; ++i) pl[i] = 0.f;

  #pragma unroll 1
  for (int nt = 0; nt < 4; ++nt) {
    int n = h * 64 + 16 * nt + l15;
    const short* baq = wtq + (4 * h + nt) * 4096 + lg * 128 + l15 * 8;
    const short* bak = wtk + (4 * h + nt) * 4096 + lg * 128 + l15 * 8;
    float biq = bq[n], bik = bk[n];
    #pragma unroll 1
    for (int mh = 0; mh < 2; ++mh) {
      f32x4 aq[4], ak[4];
      #pragma unroll
      for (int i = 0; i < 4; ++i) { aq[i] = splat4(biq); ak[i] = splat4(bik); }
      #pragma unroll
      for (int ks = 0; ks < 8; ++ks) {
        bf16x8 bqf = *(const bf16x8*)(baq + ks * 512);
        bf16x8 bkf = *(const bf16x8*)(bak + ks * 512);
        #pragma unroll
        for (int m4 = 0; m4 < 4; ++m4) {
          bf16x8 af = ld_a(activ, 16 * (4 * mh + m4) + l15, ks, lg);
          aq[m4] = __builtin_amdgcn_mfma_f32_16x16x32_bf16(af, bqf, aq[m4], 0, 0, 0);
          ak[m4] = __builtin_amdgcn_mfma_f32_16x16x32_bf16(af, bkf, ak[m4], 0, 0, 0);
        }
      }
      #pragma unroll
      for (int m4 = 0; m4 < 4; ++m4)
        #pragma unroll
        for (int r = 0; r < 4; ++r)
          pl[(4 * mh + m4) * 4 + r] += aq[m4][r] * ak[m4][r];
    }
  }
  // reduce d-partials over the 16 d-lanes; scale 1/sqrt(64)
  #pragma unroll
  for (int i = 0; i < 32; ++i) {
    float s = pl[i];
    s += __shfl_xor(s, 1);
    s += __shfl_xor(s, 2);
    s += __shfl_xor(s, 4);
    s += __shfl_xor(s, 8);
    pl[i] = s * 0.125f;
  }

  // ---------------- masked softmax, fully wave-local ----------------------
  float zmax = 0.f;  // relu floor
  #pragma unroll
  for (int i = 0; i < 32; ++i)
    zmax = fmaxf(zmax, ((mm >> i) & 1) ? pl[i] : 0.f);
  zmax = fmaxf(zmax, __shfl_xor(zmax, 16));
  zmax = fmaxf(zmax, __shfl_xor(zmax, 32));

  float esum = 0.f;
  #pragma unroll
  for (int i = 0; i < 32; ++i) {
    float ev = ((mm >> i) & 1) ? __expf(pl[i] - zmax) : 0.f;
    pl[i] = ev;
    esum += ev;
  }
  esum += __shfl_xor(esum, 16);
  esum += __shfl_xor(esum, 32);
  float inv = 1.f / (esum + 1.f);
  #pragma unroll
  for (int i = 0; i < 32; ++i) pl[i] *= inv;

  // ---------------- v: project + attn-weighted pool, direct out -----------
  #pragma unroll 1
  for (int np = 0; np < 2; ++np) {
    const short* bav0 = wtv + (4 * h + 2 * np) * 4096 + lg * 128 + l15 * 8;
    const short* bav1 = wtv + (4 * h + 2 * np + 1) * 4096 + lg * 128 + l15 * 8;
    float bi0 = bv[h * 64 + 32 * np + l15];
    float bi1 = bv[h * 64 + 32 * np + 16 + l15];
    float t0 = 0.f, t1 = 0.f;
    #pragma unroll 1
    for (int mh = 0; mh < 2; ++mh) {
      f32x4 av0[4], av1[4];
      #pragma unroll
      for (int i = 0; i < 4; ++i) { av0[i] = splat4(bi0); av1[i] = splat4(bi1); }
      #pragma unroll
      for (int ks = 0; ks < 8; ++ks) {
        bf16x8 bvf0 = *(const bf16x8*)(bav0 + ks * 512);
        bf16x8 bvf1 = *(const bf16x8*)(bav1 + ks * 512);
        #pragma unroll
        for (int m4 = 0; m4 < 4; ++m4) {
          bf16x8 af = ld_a(activ, 16 * (4 * mh + m4) + l15, ks, lg);
          av0[m4] = __builtin_amdgcn_mfma_f32_16x16x32_bf16(af, bvf0, av0[m4], 0, 0, 0);
          av1[m4] = __builtin_amdgcn_mfma_f32_16x16x32_bf16(af, bvf1, av1[m4], 0, 0, 0);
        }
      }
      #pragma unroll
      for (int m4 = 0; m4 < 4; ++m4)
        #pragma unroll
        for (int r = 0; r < 4; ++r) {
          float a = pl[(4 * mh + m4) * 4 + r];
          t0 += a * av0[m4][r];
          t1 += a * av1[m4][r];
        }
    }
    t0 += __shfl_xor(t0, 16);
    t0 += __shfl_xor(t0, 32);
    t1 += __shfl_xor(t1, 16);
    t1 += __shfl_xor(t1, 32);
    if (lg == 0) {
      out[b * 513 + h * 64 + 32 * np + l15]      = t0;
      out[b * 513 + h * 64 + 32 * np + 16 + l15] = t1;
    }
  }
}

extern "C" void kernel_launch(void* const* d_in, const int* in_sizes, int n_in,
                              void* d_out, int out_size, void* d_ws, size_t ws_size,
                              hipStream_t stream) {
  (void)in_sizes; (void)n_in; (void)out_size; (void)ws_size;
  const float* x    = (const float*)d_in[0];
  const float* Wsub = (const float*)d_in[1];
  const float* bsub = (const float*)d_in[2];
  const float* Wq   = (const float*)d_in[3];
  const float* bq   = (const float*)d_in[4];
  const float* Wk   = (const float*)d_in[5];
  const float* bk   = (const float*)d_in[6];
  const float* Wv   = (const float*)d_in[7];
  const float* bv   = (const float*)d_in[8];
  float* out = (float*)d_out;
  short* wt  = (short*)d_ws;   // 800 KB used

  prep_weights<<<1600, 256, 0, stream>>>(Wsub, Wq, Wk, Wv, wt);
  fused_kernel<<<1024, 512, 0, stream>>>(x, bsub, bq, bk, bv, wt, out);
}